// Round 6
// baseline (139.150 us; speedup 1.0000x reference)
//
#include <hip/hip_runtime.h>
#include <stdint.h>

// inputs [B=64, T=256, D=1024] f32; tanh -> sequential dual-threshold
// integrate-and-fire scan over T per (b,d). Serial over T (fp rounding of
// v depends on spike history -> no parallel scan). 65536 sequences.
//
// R6 theory: R1-R5 plateaued ~31us because vmem traffic was scalar-dword
// (256B/wave-instr, 2048 instrs/CU) — per-instruction vmem cost caps at
// ~6.9 B/cyc/CU, while every ~10 B/cyc/CU kernel on this chip (fillBuffer,
// float4 copy) is dwordx4-wide. This version makes ALL global traffic
// dwordx4 via LDS transpose tiles, and uses RAW s_barrier (own lgkmcnt
// drain only) so barriers never drain vmcnt — prefetched loads stay in
// flight across the whole scan phase (the __syncthreads vmcnt(0) drain
// is what serialized R2/R5).
#define B_DIM 64
#define T_STEPS 256
#define D_DIM 1024
#define CT 32                   // timesteps per chunk
#define CHUNKS (T_STEPS / CT)   // 8
#define TPB 256
#define DSLICE 256              // d-columns per block

// XLA/Eigen f32 tanh rational approximation — bit-exact vs jnp.tanh
// (verified rounds 1-5: absmax = 0.0). DO NOT change the FMA structure.
__device__ __forceinline__ float xla_tanhf(float x) {
    const float kClamp = 7.90531110763549805f;
    float xc = fminf(fmaxf(x, -kClamp), kClamp);
    float x2 = xc * xc;
    float p = __builtin_fmaf(x2, -2.76076847742355e-16f, 2.00018790482477e-13f);
    p = __builtin_fmaf(x2, p, -8.60467152213735e-11f);
    p = __builtin_fmaf(x2, p, 5.12229709037114e-08f);
    p = __builtin_fmaf(x2, p, 1.48572235717979e-05f);
    p = __builtin_fmaf(x2, p, 6.37261928875436e-04f);
    p = __builtin_fmaf(x2, p, 4.89352455891786e-03f);
    p = xc * p;
    float q = __builtin_fmaf(x2, 1.19825839466702e-06f, 1.18534705686654e-04f);
    q = __builtin_fmaf(x2, q, 2.26843463243900e-03f);
    q = __builtin_fmaf(x2, q, 4.89352518554385e-03f);
    float r = p / q;           // IEEE divide — required for bit-exactness
    return (fabsf(x) < 0.0004f) ? x : r;
}

// Raw workgroup barrier: drains only this wave's LDS ops, NOT vmcnt —
// global prefetch stays in flight across it. "memory" clobber stops the
// compiler moving memory ops across the barrier.
__device__ __forceinline__ void wg_barrier() {
    asm volatile("s_waitcnt lgkmcnt(0)\n\ts_barrier" ::: "memory");
}

__global__ __launch_bounds__(TPB)
void spike_scan_kernel(const float* __restrict__ in, float* __restrict__ out) {
    __shared__ float lds_in[CT][DSLICE];    // 32 KB: chunk of raw inputs
    __shared__ float lds_out[CT][DSLICE];   // 32 KB: chunk of spike outputs

    const int tid = threadIdx.x;
    const int blk = blockIdx.x;          // 0..255 -> 1 block/CU
    const int b   = blk >> 2;
    const int d0  = (blk & 3) << 8;      // 256-wide d-slice (1KB rows)
    const size_t base = (size_t)b * (T_STEPS * D_DIM) + d0;
    const int w = tid >> 6;              // wave 0..3 owns rows 8w..8w+7
    const int l = tid & 63;

    const float* inb = in + base;
    float* outb = out + base;

    float4 cur[8];
    // prologue: load chunk 0 (8 x dwordx4 per wave = 8 KB/wave in flight)
    #pragma unroll
    for (int r = 0; r < 8; ++r)
        cur[r] = ((const float4*)(inb + (size_t)(8 * w + r) * D_DIM))[l];

    float v = 0.0f;

    #pragma unroll 1
    for (int c = 0; c < CHUNKS; ++c) {
        // stage chunk c -> LDS (ds_write_b128, canonical lane->16B pattern)
        #pragma unroll
        for (int r = 0; r < 8; ++r)
            *(float4*)&lds_in[8 * w + r][4 * l] = cur[r];
        wg_barrier();                    // chunk c visible block-wide

        // prefetch chunk c+1; loads remain outstanding across the entire
        // scan + store phases (no vmcnt drain at the raw barriers)
        if (c + 1 < CHUNKS) {
            const float* inn = inb + (size_t)(c + 1) * CT * D_DIM;
            #pragma unroll
            for (int r = 0; r < 8; ++r)
                cur[r] = ((const float4*)(inn + (size_t)(8 * w + r) * D_DIM))[l];
        }
        __builtin_amdgcn_sched_barrier(0);   // pin load issue before the scan

        // scan: batch 32 LDS reads + 32 tanh (max ILP), then the serial
        // v-chain; spikes land in the LDS out-tile (column stride-4B:
        // 2 lanes/bank = conflict-free)
        float rr[CT];
        #pragma unroll
        for (int u = 0; u < CT; ++u) rr[u] = lds_in[u][tid];
        #pragma unroll
        for (int u = 0; u < CT; ++u) rr[u] = xla_tanhf(rr[u]);
        #pragma unroll
        for (int u = 0; u < CT; ++u) {
            v = __builtin_fmaf(rr[u], 0.01f, v);    // v += r*DT
            float sp = (v >= 1.0f)  ? 1.0f : 0.0f;
            float sn = (v <= -1.0f) ? 1.0f : 0.0f;
            v = (v - sp) + sn;                      // subtractive reset (exact)
            lds_out[u][tid] = (sp - sn) * 100.0f;   // ±100.0f exactly
        }
        wg_barrier();                    // out-tile complete block-wide

        // wide store: rows of the out-tile as dwordx4 (1 KB/wave-instr)
        float* outc = outb + (size_t)c * CT * D_DIM;
        #pragma unroll
        for (int r = 0; r < 8; ++r) {
            float4 o4 = *(const float4*)&lds_out[8 * w + r][4 * l];
            ((float4*)(outc + (size_t)(8 * w + r) * D_DIM))[l] = o4;
        }
    }
}

extern "C" void kernel_launch(void* const* d_in, const int* in_sizes, int n_in,
                              void* d_out, int out_size, void* d_ws, size_t ws_size,
                              hipStream_t stream) {
    const float* in = (const float*)d_in[0];
    float* out = (float*)d_out;
    dim3 block(TPB);
    dim3 grid(B_DIM * (D_DIM / DSLICE));  // 256 blocks -> 1 per CU
    spike_scan_kernel<<<grid, block, 0, stream>>>(in, out);
}